// Round 7
// baseline (474.411 us; speedup 1.0000x reference)
//
#include <hip/hip_runtime.h>
#include <hip/hip_bf16.h>

// B=4, S=2048, D_MODEL=1024, H=16, HEAD=64. Inputs fp32, output fp32.
#define S_LEN 2048
#define DM    1024
#define NH    16
#define HD    64

typedef __attribute__((ext_vector_type(8))) short short8;   // 8 bf16 (MFMA A/B frag)
typedef __attribute__((ext_vector_type(4))) short short4v;  // 4 bf16 (8B store)
typedef __attribute__((ext_vector_type(4))) float f32x4;    // MFMA C/D frag

// fp32 -> bf16 RNE (weight/output paths)
__device__ __forceinline__ short f2bf(float f) {
    union { float f; unsigned u; } x; x.f = f;
    unsigned u = x.u;
    return (short)((u + 0x7FFFu + ((u >> 16) & 1u)) >> 16);
}
// round-half-up variants (2 VALU; bias negligible for continuous data)
__device__ __forceinline__ short f2bf_ru(float f) {
    return (short)((__float_as_uint(f) + 0x8000u) >> 16);
}
__device__ __forceinline__ unsigned pk2bf(float a, float b) {
    unsigned ua = __float_as_uint(a) + 0x8000u;
    unsigned ub = __float_as_uint(b) + 0x8000u;
    return (ua >> 16) | (ub & 0xFFFF0000u);
}
__device__ __forceinline__ float fexp2(float x) {
#if __has_builtin(__builtin_amdgcn_exp2f)
    return __builtin_amdgcn_exp2f(x);
#else
    return exp2f(x);
#endif
}
// async global->LDS, 16B per lane (wave-uniform base + lane*16 dest)
__device__ __forceinline__ void gload_lds16(const void* g, void* l) {
    __builtin_amdgcn_global_load_lds(
        (const __attribute__((address_space(1))) unsigned int*)g,
        (__attribute__((address_space(3))) unsigned int*)l, 16, 0, 0);
}

// ---------------------------------------------------------------------------
// Kernel 1: W [K][N] fp32 -> WT [N][K] bf16 for Wq/Wk/Wv (blockIdx.z)
// ---------------------------------------------------------------------------
__global__ void wt_kernel(const float* __restrict__ Wq, const float* __restrict__ Wk,
                          const float* __restrict__ Wv, short* __restrict__ wt_base) {
    __shared__ float t[32][33];
    const float* W = (blockIdx.z == 0) ? Wq : (blockIdx.z == 1 ? Wk : Wv);
    short* WT = wt_base + (size_t)blockIdx.z * DM * DM;
    int kb = blockIdx.x * 32, nb = blockIdx.y * 32;
    int tx = threadIdx.x, ty = threadIdx.y;  // 32 x 8
#pragma unroll
    for (int r = 0; r < 4; r++)
        t[ty + 8 * r][tx] = W[(size_t)(kb + ty + 8 * r) * DM + nb + tx];
    __syncthreads();
#pragma unroll
    for (int r = 0; r < 4; r++)
        WT[(size_t)(nb + ty + 8 * r) * DM + kb + tx] = f2bf(t[tx][ty + 8 * r]);
}

// ---------------------------------------------------------------------------
// Kernel 2: fused projections (z = 0:Q, 1:K, 2:V).  [frozen from R5]
// 512-thr blocks, tile 128(M) x 256(N), BK=32; 8 waves, each the m97 body.
// LDS 48KB x2buf -> 3 blocks/CU; grid 768 = one dispatch round, no tail.
// Staging issued at iter top. Grid 1D chunked XCD swizzle (768 = 8 x 96).
// ---------------------------------------------------------------------------
__global__ __launch_bounds__(512, 2) void projf_kernel(
        const float* __restrict__ Xq, const float* __restrict__ Xk,
        const float* __restrict__ Xv, const short* __restrict__ WT3,
        const float* __restrict__ bq, const float* __restrict__ bk,
        const float* __restrict__ bv,
        short* __restrict__ Qh, short* __restrict__ Kh, short* __restrict__ Vt,
        float qscale) {
    __shared__ __align__(16) short As[2][128 * 32];   // bf16 A tile,  8KB/buf
    __shared__ __align__(16) short Bs[2][256 * 32];   // bf16 B tile, 16KB/buf
    const int bid = blockIdx.x;
    const int swz = (bid & 7) * 96 + (bid >> 3);
    const int nx = swz & 3;          // n-tile (fastest logical: 4 share X panel)
    const int my = (swz >> 2) & 63;  // m-tile
    const int z  = swz >> 8;         // matrix select (4*64 = 256 per z)

    const float* X = (z == 0) ? Xq : (z == 1) ? Xk : Xv;
    const short* WT = WT3 + (size_t)z * DM * DM;
    const float* bias = (z == 0) ? bq : (z == 1) ? bk : bv;
    short* out = (z == 0) ? Qh : (z == 1) ? Kh : Vt;
    const float scale = (z == 0) ? qscale : 1.0f;
    const int mode = (z == 2);

    const int tid = threadIdx.x;
    const int lane = tid & 63, w = tid >> 6;          // 8 waves
    const int l15 = lane & 15, quad = lane >> 4;
    const int n0 = nx * 256, m0 = my * 128;
    const int wm = (w & 1) * 64, wn = (w >> 1) * 64;  // 2M x 4N wave grid
    const int arow = tid >> 2;          // A staging: 4 threads/row
    const int ako  = (tid & 3) * 8;     // 8 floats (=8 bf16 out) per thread

    const float* xb = X + (size_t)m0 * DM;

    f32x4 acc[4][4];
#pragma unroll
    for (int i = 0; i < 4; i++)
#pragma unroll
        for (int j = 0; j < 4; j++) { acc[i][j][0] = 0.f; acc[i][j][1] = 0.f; acc[i][j][2] = 0.f; acc[i][j][3] = 0.f; }

    auto stageB = [&](int k0, int bi) {
#pragma unroll
        for (int it = 0; it < 2; it++) {
            int c = it * 512 + tid;
            int row = c >> 2, ko = (c & 3) * 8;
            gload_lds16(WT + (size_t)(n0 + row) * DM + k0 + ko, Bs[bi] + c * 8);
        }
    };

    // ---- prologue: stage tile 0 into buf 0 ----
    float4 a0, a1;
    a0 = *(const float4*)(xb + (size_t)arow * DM + ako);
    a1 = *(const float4*)(xb + (size_t)arow * DM + ako + 4);
    stageB(0, 0);
    {
        uint4 p;
        p.x = pk2bf(a0.x, a0.y); p.y = pk2bf(a0.z, a0.w);
        p.z = pk2bf(a1.x, a1.y); p.w = pk2bf(a1.z, a1.w);
        *(uint4*)(As[0] + arow * 32 + ako) = p;
    }

    for (int t = 0; t < 32; t++) {
        const int bi = t & 1;
        const int kn = t * 32 + 32;     // next tile's k0
        __syncthreads();                // tile t staged (vmcnt+lgkm drained)

        if (t < 31) {                   // STAGE AT TOP: max cover before use
            a0 = *(const float4*)(xb + (size_t)arow * DM + kn + ako);
            a1 = *(const float4*)(xb + (size_t)arow * DM + kn + ako + 4);
            stageB(kn, bi ^ 1);
        }

        short8 af[4], bf[4];
#pragma unroll
        for (int i = 0; i < 4; i++)
            af[i] = *(const short8*)(As[bi] + (wm + i * 16 + l15) * 32 + quad * 8);
#pragma unroll
        for (int j = 0; j < 4; j++)
            bf[j] = *(const short8*)(Bs[bi] + (wn + j * 16 + l15) * 32 + quad * 8);

#pragma unroll
        for (int i = 0; i < 4; i++)
#pragma unroll
            for (int j = 0; j < 4; j++)
                acc[i][j] = __builtin_amdgcn_mfma_f32_16x16x32_bf16(af[i], bf[j], acc[i][j], 0, 0, 0);

        if (t < 31) {                   // convert+write A for tile t+1
            uint4 p;
            p.x = pk2bf(a0.x, a0.y); p.y = pk2bf(a0.z, a0.w);
            p.z = pk2bf(a1.x, a1.y); p.w = pk2bf(a1.z, a1.w);
            *(uint4*)(As[bi ^ 1] + arow * 32 + ako) = p;
        }
    }

    // ---- epilogue ----
#pragma unroll
    for (int j = 0; j < 4; j++) {
        int col = n0 + wn + j * 16 + l15;
        float bv_ = bias[col];
        int h = col >> 6, d = col & 63;
#pragma unroll
        for (int i = 0; i < 4; i++) {
            int rowbase = m0 + wm + i * 16 + quad * 4;
            int bb = rowbase >> 11, s0 = rowbase & 2047;
            if (mode == 0) {
#pragma unroll
                for (int r = 0; r < 4; r++)
                    out[((size_t)(bb * NH + h) * S_LEN + (s0 + r)) * HD + d] =
                        f2bf((acc[i][j][r] + bv_) * scale);
            } else {
                short4v pk;
#pragma unroll
                for (int r = 0; r < 4; r++) pk[r] = f2bf((acc[i][j][r] + bv_) * scale);
                *(short4v*)(out + ((size_t)(bb * NH + h) * HD + d) * S_LEN + s0) = pk;
            }
        }
    }
}

// ---------------------------------------------------------------------------
// Kernel 3: attention, R7: NO K/V LDS STAGING, NO BARRIERS.
// Rationale: K/V per head = 256KB each -> fully L2-resident (XCD swizzle
// groups a head's 16 q-tiles on one XCD). LDS staging + barrier + vmcnt
// drain was the phase-lock (R5/R6 evidence); guide common-mistake #7 says
// staging L2-fit data is pure overhead. K/V frags now read DIRECTLY from
// global (L2 hit, ~200cy, hidden by 16 waves/CU TLP + in-iter overlap):
//   kf[nb][hf]: K[kt+nb*16+l15][quad*8 + hf*32]  (16B dwordx4)
//   vf[dd][hf]: Vt[dd*16+l15][kt + quad*8 + hf*32]
// byte-identical data the LDS reads used to deliver. Waves fully
// independent: compiler pipelines across iterations, no phase-locking.
// P path: R5-proven wave-private LDS (18KB), lgkmcnt(0) only (wave-local).
// V loads issued between QK^T and exp2 phase: L2 latency hides under exp2.
// LDS 18KB, 256 thr -> 4 blocks/CU x 256 CU = grid 1024, one exact round,
// 16 waves/CU. launch_bounds(256,4) caps VGPR at 128.
// Grid 1D chunked XCD swizzle: 1024 = 8 XCDs x 128.
// ---------------------------------------------------------------------------
__global__ __launch_bounds__(256, 4) void attn_kernel(
        const short* __restrict__ Q, const short* __restrict__ K,
        const short* __restrict__ V, float* __restrict__ out) {
    __shared__ __align__(16) short ps[4][2][16 * 72]; // [wave][strip] 18KB
    const int bid = blockIdx.x;
    const int swz = (bid & 7) * 128 + (bid >> 3);
    const int qi = swz & 15;         // q-tile (fastest in logical order)
    const int h  = (swz >> 4) & 15;  // head
    const int b  = swz >> 8;         // batch

    const int tid = threadIdx.x;
    const int lane = tid & 63, w = tid >> 6;          // 4 waves
    const int l15 = lane & 15, quad = lane >> 4;
    const int q0 = qi * 128;
    const size_t bh = (size_t)(b * NH + h);
    const short* qp = Q + bh * S_LEN * HD;
    const short* kp = K + bh * S_LEN * HD;
    const short* vp = V + bh * (size_t)HD * S_LEN;

    short8 qa[2][2];
#pragma unroll
    for (int s = 0; s < 2; s++) {
        const short* qr = qp + (size_t)(q0 + w * 32 + s * 16 + l15) * HD + quad * 8;
        qa[s][0] = *(const short8*)(qr);
        qa[s][1] = *(const short8*)(qr + 32);
    }

    // per-lane K/V fragment base pointers (row fixed, col walks with kt)
    const short* kbase0 = kp + (size_t)l15 * HD + quad * 8;        // + nb*16*HD + kt*HD
    const short* vbase  = vp + (size_t)l15 * S_LEN + quad * 8;     // + dd*16*S_LEN + kt

    f32x4 o[2][4];
    float lsum[2][4];
#pragma unroll
    for (int s = 0; s < 2; s++)
#pragma unroll
        for (int d = 0; d < 4; d++) {
            o[s][d][0] = 0.f; o[s][d][1] = 0.f; o[s][d][2] = 0.f; o[s][d][3] = 0.f;
            lsum[s][d] = 0.f;
        }

    for (int t = 0; t < 32; t++) {
        const int kt = t << 6;

        // ---- K frags direct from global (L2) + QK^T ----
        short8 kf[4][2];
#pragma unroll
        for (int nb = 0; nb < 4; nb++) {
            const short* kr = kbase0 + (size_t)(kt + nb * 16) * HD;
            kf[nb][0] = *(const short8*)(kr);
            kf[nb][1] = *(const short8*)(kr + 32);
        }
        f32x4 sacc[2][4];
#pragma unroll
        for (int nb = 0; nb < 4; nb++)
#pragma unroll
            for (int s = 0; s < 2; s++) {
                f32x4 zz; zz[0] = 0.f; zz[1] = 0.f; zz[2] = 0.f; zz[3] = 0.f;
                zz = __builtin_amdgcn_mfma_f32_16x16x32_bf16(qa[s][0], kf[nb][0], zz, 0, 0, 0);
                sacc[s][nb] = __builtin_amdgcn_mfma_f32_16x16x32_bf16(qa[s][1], kf[nb][1], zz, 0, 0, 0);
            }

        // ---- V frags issued NOW: L2 latency hides under exp2/P phase ----
        short8 vf[4][2];
#pragma unroll
        for (int dd = 0; dd < 4; dd++) {
            const short* vr = vbase + (size_t)(dd * 16) * S_LEN + kt;
            vf[dd][0] = *(const short8*)(vr);
            vf[dd][1] = *(const short8*)(vr + 32);
        }

        // ---- P = exp2(S'); partial row-sums; P -> wave-private LDS ----
#pragma unroll
        for (int s = 0; s < 2; s++)
#pragma unroll
            for (int r = 0; r < 4; r++)
#pragma unroll
                for (int nb = 0; nb < 4; nb++) {
                    float p = fexp2(sacc[s][nb][r]);
                    lsum[s][r] += p;
                    ps[w][s][(quad * 4 + r) * 72 + nb * 16 + l15] = f2bf_ru(p);
                }
        asm volatile("s_waitcnt lgkmcnt(0)" ::: "memory");
        short8 pa[2][2];
#pragma unroll
        for (int s = 0; s < 2; s++) {
            pa[s][0] = *(const short8*)(&ps[w][s][l15 * 72 + quad * 8]);
            pa[s][1] = *(const short8*)(&ps[w][s][l15 * 72 + 32 + quad * 8]);
        }

        // ---- PV ----
#pragma unroll
        for (int dd = 0; dd < 4; dd++)
#pragma unroll
            for (int s = 0; s < 2; s++) {
                o[s][dd] = __builtin_amdgcn_mfma_f32_16x16x32_bf16(pa[s][0], vf[dd][0], o[s][dd], 0, 0, 0);
                o[s][dd] = __builtin_amdgcn_mfma_f32_16x16x32_bf16(pa[s][1], vf[dd][1], o[s][dd], 0, 0, 0);
            }
    }

    // ---- deferred l reduction + epilogue ----
#pragma unroll
    for (int s = 0; s < 2; s++) {
#pragma unroll
        for (int r = 0; r < 4; r++) {
            float l = lsum[s][r];
            l += __shfl_xor(l, 1);
            l += __shfl_xor(l, 2);
            l += __shfl_xor(l, 4);
            l += __shfl_xor(l, 8);
            lsum[s][r] = 1.f / l;
        }
        float* orow = out + ((size_t)b * S_LEN + q0 + w * 32 + s * 16 + quad * 4) * DM + h * HD + l15;
#pragma unroll
        for (int r = 0; r < 4; r++)
#pragma unroll
            for (int dd = 0; dd < 4; dd++)
                orow[(size_t)r * DM + dd * 16] = o[s][dd][r] * lsum[s][r];
    }
}

// ---------------------------------------------------------------------------
// ws (56.6 MB): [0,6.3M) WT x3 bf16 | Qh | Kh | Vt (16.8M each)
// ---------------------------------------------------------------------------
extern "C" void kernel_launch(void* const* d_in, const int* in_sizes, int n_in,
                              void* d_out, int out_size, void* d_ws, size_t ws_size,
                              hipStream_t stream) {
    const float* query  = (const float*)d_in[0];
    const float* key_in = (const float*)d_in[1];
    const float* value  = (const float*)d_in[2];
    const float* Wq = (const float*)d_in[3];
    const float* bq = (const float*)d_in[4];
    const float* Wk = (const float*)d_in[5];
    const float* bk = (const float*)d_in[6];
    const float* Wv = (const float*)d_in[7];
    const float* bv = (const float*)d_in[8];

    short* wt = (short*)d_ws;
    short* Qh = wt + 3 * 1048576;
    short* Kh = Qh + 8388608;
    short* Vt = Kh + 8388608;
    float* out = (float*)d_out;

    const float QSCALE = 0.125f * 1.44269504088896340736f;  // 1/sqrt(64) * log2(e)

    wt_kernel<<<dim3(32, 32, 3), dim3(32, 8), 0, stream>>>(Wq, Wk, Wv, wt);
    projf_kernel<<<dim3(768), 512, 0, stream>>>(query, key_in, value, wt,
                                                bq, bk, bv, Qh, Kh, Vt, QSCALE);
    attn_kernel<<<dim3(1024), 256, 0, stream>>>(Qh, Kh, Vt, out);
}

// Round 8
// 322.615 us; speedup vs baseline: 1.4705x; 1.4705x over previous
//
#include <hip/hip_runtime.h>
#include <hip/hip_bf16.h>

// B=4, S=2048, D_MODEL=1024, H=16, HEAD=64. Inputs fp32, output fp32.
#define S_LEN 2048
#define DM    1024
#define NH    16
#define HD    64

typedef __attribute__((ext_vector_type(8))) short short8;   // 8 bf16 (MFMA A/B frag)
typedef __attribute__((ext_vector_type(4))) short short4v;  // 4 bf16 (8B store)
typedef __attribute__((ext_vector_type(4))) float f32x4;    // MFMA C/D frag

// fp32 -> bf16 RNE (weight/output paths)
__device__ __forceinline__ short f2bf(float f) {
    union { float f; unsigned u; } x; x.f = f;
    unsigned u = x.u;
    return (short)((u + 0x7FFFu + ((u >> 16) & 1u)) >> 16);
}
// round-half-up variants (2 VALU; bias negligible for continuous data)
__device__ __forceinline__ short f2bf_ru(float f) {
    return (short)((__float_as_uint(f) + 0x8000u) >> 16);
}
__device__ __forceinline__ unsigned pk2bf(float a, float b) {
    unsigned ua = __float_as_uint(a) + 0x8000u;
    unsigned ub = __float_as_uint(b) + 0x8000u;
    return (ua >> 16) | (ub & 0xFFFF0000u);
}
__device__ __forceinline__ float fexp2(float x) {
#if __has_builtin(__builtin_amdgcn_exp2f)
    return __builtin_amdgcn_exp2f(x);
#else
    return exp2f(x);
#endif
}
// async global->LDS, 16B per lane (wave-uniform base + lane*16 dest)
__device__ __forceinline__ void gload_lds16(const void* g, void* l) {
    __builtin_amdgcn_global_load_lds(
        (const __attribute__((address_space(1))) unsigned int*)g,
        (__attribute__((address_space(3))) unsigned int*)l, 16, 0, 0);
}

// ---------------------------------------------------------------------------
// Kernel 1: W [K][N] fp32 -> WT [N][K] bf16 for Wq/Wk/Wv (blockIdx.z)
// ---------------------------------------------------------------------------
__global__ void wt_kernel(const float* __restrict__ Wq, const float* __restrict__ Wk,
                          const float* __restrict__ Wv, short* __restrict__ wt_base) {
    __shared__ float t[32][33];
    const float* W = (blockIdx.z == 0) ? Wq : (blockIdx.z == 1 ? Wk : Wv);
    short* WT = wt_base + (size_t)blockIdx.z * DM * DM;
    int kb = blockIdx.x * 32, nb = blockIdx.y * 32;
    int tx = threadIdx.x, ty = threadIdx.y;  // 32 x 8
#pragma unroll
    for (int r = 0; r < 4; r++)
        t[ty + 8 * r][tx] = W[(size_t)(kb + ty + 8 * r) * DM + nb + tx];
    __syncthreads();
#pragma unroll
    for (int r = 0; r < 4; r++)
        WT[(size_t)(nb + ty + 8 * r) * DM + kb + tx] = f2bf(t[tx][ty + 8 * r]);
}

// ---------------------------------------------------------------------------
// Kernel 2: fused projections (z = 0:Q, 1:K, 2:V).  [frozen from R5]
// 512-thr blocks, tile 128(M) x 256(N), BK=32; 8 waves, each the m97 body.
// LDS 48KB x2buf -> 3 blocks/CU; grid 768 = one dispatch round, no tail.
// Staging issued at iter top. Grid 1D chunked XCD swizzle (768 = 8 x 96).
// ---------------------------------------------------------------------------
__global__ __launch_bounds__(512, 2) void projf_kernel(
        const float* __restrict__ Xq, const float* __restrict__ Xk,
        const float* __restrict__ Xv, const short* __restrict__ WT3,
        const float* __restrict__ bq, const float* __restrict__ bk,
        const float* __restrict__ bv,
        short* __restrict__ Qh, short* __restrict__ Kh, short* __restrict__ Vt,
        float qscale) {
    __shared__ __align__(16) short As[2][128 * 32];   // bf16 A tile,  8KB/buf
    __shared__ __align__(16) short Bs[2][256 * 32];   // bf16 B tile, 16KB/buf
    const int bid = blockIdx.x;
    const int swz = (bid & 7) * 96 + (bid >> 3);
    const int nx = swz & 3;          // n-tile (fastest logical: 4 share X panel)
    const int my = (swz >> 2) & 63;  // m-tile
    const int z  = swz >> 8;         // matrix select (4*64 = 256 per z)

    const float* X = (z == 0) ? Xq : (z == 1) ? Xk : Xv;
    const short* WT = WT3 + (size_t)z * DM * DM;
    const float* bias = (z == 0) ? bq : (z == 1) ? bk : bv;
    short* out = (z == 0) ? Qh : (z == 1) ? Kh : Vt;
    const float scale = (z == 0) ? qscale : 1.0f;
    const int mode = (z == 2);

    const int tid = threadIdx.x;
    const int lane = tid & 63, w = tid >> 6;          // 8 waves
    const int l15 = lane & 15, quad = lane >> 4;
    const int n0 = nx * 256, m0 = my * 128;
    const int wm = (w & 1) * 64, wn = (w >> 1) * 64;  // 2M x 4N wave grid
    const int arow = tid >> 2;          // A staging: 4 threads/row
    const int ako  = (tid & 3) * 8;     // 8 floats (=8 bf16 out) per thread

    const float* xb = X + (size_t)m0 * DM;

    f32x4 acc[4][4];
#pragma unroll
    for (int i = 0; i < 4; i++)
#pragma unroll
        for (int j = 0; j < 4; j++) { acc[i][j][0] = 0.f; acc[i][j][1] = 0.f; acc[i][j][2] = 0.f; acc[i][j][3] = 0.f; }

    auto stageB = [&](int k0, int bi) {
#pragma unroll
        for (int it = 0; it < 2; it++) {
            int c = it * 512 + tid;
            int row = c >> 2, ko = (c & 3) * 8;
            gload_lds16(WT + (size_t)(n0 + row) * DM + k0 + ko, Bs[bi] + c * 8);
        }
    };

    // ---- prologue: stage tile 0 into buf 0 ----
    float4 a0, a1;
    a0 = *(const float4*)(xb + (size_t)arow * DM + ako);
    a1 = *(const float4*)(xb + (size_t)arow * DM + ako + 4);
    stageB(0, 0);
    {
        uint4 p;
        p.x = pk2bf(a0.x, a0.y); p.y = pk2bf(a0.z, a0.w);
        p.z = pk2bf(a1.x, a1.y); p.w = pk2bf(a1.z, a1.w);
        *(uint4*)(As[0] + arow * 32 + ako) = p;
    }

    for (int t = 0; t < 32; t++) {
        const int bi = t & 1;
        const int kn = t * 32 + 32;     // next tile's k0
        __syncthreads();                // tile t staged (vmcnt+lgkm drained)

        if (t < 31) {                   // STAGE AT TOP: max cover before use
            a0 = *(const float4*)(xb + (size_t)arow * DM + kn + ako);
            a1 = *(const float4*)(xb + (size_t)arow * DM + kn + ako + 4);
            stageB(kn, bi ^ 1);
        }

        short8 af[4], bf[4];
#pragma unroll
        for (int i = 0; i < 4; i++)
            af[i] = *(const short8*)(As[bi] + (wm + i * 16 + l15) * 32 + quad * 8);
#pragma unroll
        for (int j = 0; j < 4; j++)
            bf[j] = *(const short8*)(Bs[bi] + (wn + j * 16 + l15) * 32 + quad * 8);

#pragma unroll
        for (int i = 0; i < 4; i++)
#pragma unroll
            for (int j = 0; j < 4; j++)
                acc[i][j] = __builtin_amdgcn_mfma_f32_16x16x32_bf16(af[i], bf[j], acc[i][j], 0, 0, 0);

        if (t < 31) {                   // convert+write A for tile t+1
            uint4 p;
            p.x = pk2bf(a0.x, a0.y); p.y = pk2bf(a0.z, a0.w);
            p.z = pk2bf(a1.x, a1.y); p.w = pk2bf(a1.z, a1.w);
            *(uint4*)(As[bi ^ 1] + arow * 32 + ako) = p;
        }
    }

    // ---- epilogue ----
#pragma unroll
    for (int j = 0; j < 4; j++) {
        int col = n0 + wn + j * 16 + l15;
        float bv_ = bias[col];
        int h = col >> 6, d = col & 63;
#pragma unroll
        for (int i = 0; i < 4; i++) {
            int rowbase = m0 + wm + i * 16 + quad * 4;
            int bb = rowbase >> 11, s0 = rowbase & 2047;
            if (mode == 0) {
#pragma unroll
                for (int r = 0; r < 4; r++)
                    out[((size_t)(bb * NH + h) * S_LEN + (s0 + r)) * HD + d] =
                        f2bf((acc[i][j][r] + bv_) * scale);
            } else {
                short4v pk;
#pragma unroll
                for (int r = 0; r < 4; r++) pk[r] = f2bf((acc[i][j][r] + bv_) * scale);
                *(short4v*)(out + ((size_t)(bb * NH + h) * HD + d) * S_LEN + s0) = pk;
            }
        }
    }
}

// ---------------------------------------------------------------------------
// Kernel 3: attention. [R5-proven structure restored after R6/R7 probes]
// R7 evidence: direct-from-global K/V frags serialize ~16 L2 loads/iter/wave
// (300cy each, VGPR-64 schedule) AND multiply L2 line-traffic by the wave
// count -- LDS staging dedups reads across waves and converts L2 latency
// into fire-and-forget gload_lds + fast ds_reads. Staging stays.
// 512 thr / 8 waves, q-tile 256; K/V double-buffered via gload_lds (1 K +
// 1 V inst/thread/iter); ONE barrier/iter; no-max softmax (Q pre-scaled by
// 0.125*log2e, exp2); P via wave-private LDS (lgkm drain only).
// LDS 68KB -> 2 blocks/CU = 16 waves/CU; grid 512 = one exact round.
// R8 addition: T5 s_setprio(1/0) around both MFMA clusters (m191: +4-7% on
// 2-phase attn; favors MFMA-entering waves among 16 contending waves/CU).
// Grid 1D chunked XCD swizzle: 512 = 8 XCDs x 64.
// ---------------------------------------------------------------------------
__global__ __launch_bounds__(512, 2) void attn_kernel(
        const short* __restrict__ Q, const short* __restrict__ K,
        const short* __restrict__ V, float* __restrict__ out) {
    __shared__ __align__(16) short Ks[2][2][64][32];  // [buf][half][key-row][32] 16KB
    __shared__ __align__(16) short Vs[2][2][64][32];  // [buf][half][d-row][32]   16KB
    __shared__ __align__(16) short ps[8][2][16 * 72]; // [wave][strip]            36KB
    const int bid = blockIdx.x;
    const int swz = (bid & 7) * 64 + (bid >> 3);
    const int qi = swz & 7;          // q-tile (fastest in logical order)
    const int h  = (swz >> 3) & 15;  // head
    const int b  = swz >> 7;         // batch (8*16 = 128 per b)

    const int tid = threadIdx.x;
    const int lane = tid & 63, w = tid >> 6;          // 8 waves
    const int l15 = lane & 15, quad = lane >> 4;
    const int q0 = qi * 256;
    const size_t bh = (size_t)(b * NH + h);
    const short* qp = Q + bh * S_LEN * HD;
    const short* kp = K + bh * S_LEN * HD;
    const short* vp = V + bh * (size_t)HD * S_LEN;

    short8 qa[2][2];
#pragma unroll
    for (int s = 0; s < 2; s++) {
        const short* qr = qp + (size_t)(q0 + w * 32 + s * 16 + l15) * HD + quad * 8;
        qa[s][0] = *(const short8*)(qr);
        qa[s][1] = *(const short8*)(qr + 32);
    }

    f32x4 o[2][4];
    float lsum[2][4];
#pragma unroll
    for (int s = 0; s < 2; s++)
#pragma unroll
        for (int d = 0; d < 4; d++) {
            o[s][d][0] = 0.f; o[s][d][1] = 0.f; o[s][d][2] = 0.f; o[s][d][3] = 0.f;
            lsum[s][d] = 0.f;
        }

    // 512 slots(K) + 512 slots(V), one 16B inst each per thread
    auto stageKV = [&](int kt, int bi) {
        int c = tid;
        int half = c >> 8, row = (c >> 2) & 63, chunk = c & 3;
        int co = half * 32 + chunk * 8;
        gload_lds16(kp + (size_t)(kt + row) * HD + co, &Ks[bi][0][0][0] + c * 8);
        gload_lds16(vp + (size_t)row * S_LEN + kt + co, &Vs[bi][0][0][0] + c * 8);
    };

    stageKV(0, 0);

    for (int t = 0; t < 32; t++) {
        const int bi = t & 1;
        __syncthreads();                 // tile t ready (vmcnt drained); buf^1 free
        if (t < 31) stageKV((t + 1) << 6, bi ^ 1);   // issue next tile NOW

        // ---- K frags from LDS (shared by all waves) + QK^T ----
        short8 kf[4][2];
#pragma unroll
        for (int nb = 0; nb < 4; nb++) {
            kf[nb][0] = *(const short8*)(&Ks[bi][0][nb * 16 + l15][quad * 8]);
            kf[nb][1] = *(const short8*)(&Ks[bi][1][nb * 16 + l15][quad * 8]);
        }
        f32x4 sacc[2][4];
        __builtin_amdgcn_s_setprio(1);
#pragma unroll
        for (int nb = 0; nb < 4; nb++)
#pragma unroll
            for (int s = 0; s < 2; s++) {
                f32x4 zz; zz[0] = 0.f; zz[1] = 0.f; zz[2] = 0.f; zz[3] = 0.f;
                zz = __builtin_amdgcn_mfma_f32_16x16x32_bf16(qa[s][0], kf[nb][0], zz, 0, 0, 0);
                sacc[s][nb] = __builtin_amdgcn_mfma_f32_16x16x32_bf16(qa[s][1], kf[nb][1], zz, 0, 0, 0);
            }
        __builtin_amdgcn_s_setprio(0);
        // ---- P = exp2(S'); partial row-sums; P -> wave-private LDS ----
#pragma unroll
        for (int s = 0; s < 2; s++)
#pragma unroll
            for (int r = 0; r < 4; r++)
#pragma unroll
                for (int nb = 0; nb < 4; nb++) {
                    float p = fexp2(sacc[s][nb][r]);
                    lsum[s][r] += p;
                    ps[w][s][(quad * 4 + r) * 72 + nb * 16 + l15] = f2bf_ru(p);
                }
        asm volatile("s_waitcnt lgkmcnt(0)" ::: "memory");
        short8 pa[2][2];
#pragma unroll
        for (int s = 0; s < 2; s++) {
            pa[s][0] = *(const short8*)(&ps[w][s][l15 * 72 + quad * 8]);
            pa[s][1] = *(const short8*)(&ps[w][s][l15 * 72 + 32 + quad * 8]);
        }
        // ---- V frags from LDS + PV ----
        __builtin_amdgcn_s_setprio(1);
#pragma unroll
        for (int dd = 0; dd < 4; dd++) {
            short8 v0 = *(const short8*)(&Vs[bi][0][dd * 16 + l15][quad * 8]);
            short8 v1 = *(const short8*)(&Vs[bi][1][dd * 16 + l15][quad * 8]);
#pragma unroll
            for (int s = 0; s < 2; s++) {
                o[s][dd] = __builtin_amdgcn_mfma_f32_16x16x32_bf16(pa[s][0], v0, o[s][dd], 0, 0, 0);
                o[s][dd] = __builtin_amdgcn_mfma_f32_16x16x32_bf16(pa[s][1], v1, o[s][dd], 0, 0, 0);
            }
        }
        __builtin_amdgcn_s_setprio(0);
    }

    // ---- deferred l reduction + epilogue ----
#pragma unroll
    for (int s = 0; s < 2; s++) {
#pragma unroll
        for (int r = 0; r < 4; r++) {
            float l = lsum[s][r];
            l += __shfl_xor(l, 1);
            l += __shfl_xor(l, 2);
            l += __shfl_xor(l, 4);
            l += __shfl_xor(l, 8);
            lsum[s][r] = 1.f / l;
        }
        float* orow = out + ((size_t)b * S_LEN + q0 + w * 32 + s * 16 + quad * 4) * DM + h * HD + l15;
#pragma unroll
        for (int r = 0; r < 4; r++)
#pragma unroll
            for (int dd = 0; dd < 4; dd++)
                orow[(size_t)r * DM + dd * 16] = o[s][dd][r] * lsum[s][r];
    }
}

// ---------------------------------------------------------------------------
// ws (56.6 MB): [0,6.3M) WT x3 bf16 | Qh | Kh | Vt (16.8M each)
// ---------------------------------------------------------------------------
extern "C" void kernel_launch(void* const* d_in, const int* in_sizes, int n_in,
                              void* d_out, int out_size, void* d_ws, size_t ws_size,
                              hipStream_t stream) {
    const float* query  = (const float*)d_in[0];
    const float* key_in = (const float*)d_in[1];
    const float* value  = (const float*)d_in[2];
    const float* Wq = (const float*)d_in[3];
    const float* bq = (const float*)d_in[4];
    const float* Wk = (const float*)d_in[5];
    const float* bk = (const float*)d_in[6];
    const float* Wv = (const float*)d_in[7];
    const float* bv = (const float*)d_in[8];

    short* wt = (short*)d_ws;
    short* Qh = wt + 3 * 1048576;
    short* Kh = Qh + 8388608;
    short* Vt = Kh + 8388608;
    float* out = (float*)d_out;

    const float QSCALE = 0.125f * 1.44269504088896340736f;  // 1/sqrt(64) * log2(e)

    wt_kernel<<<dim3(32, 32, 3), dim3(32, 8), 0, stream>>>(Wq, Wk, Wv, wt);
    projf_kernel<<<dim3(768), 512, 0, stream>>>(query, key_in, value, wt,
                                                bq, bk, bv, Qh, Kh, Vt, QSCALE);
    attn_kernel<<<dim3(512), 512, 0, stream>>>(Qh, Kh, Vt, out);
}

// Round 9
// 314.439 us; speedup vs baseline: 1.5088x; 1.0260x over previous
//
#include <hip/hip_runtime.h>
#include <hip/hip_bf16.h>

// B=4, S=2048, D_MODEL=1024, H=16, HEAD=64. Inputs fp32, output fp32.
#define S_LEN 2048
#define DM    1024
#define NH    16
#define HD    64

typedef __attribute__((ext_vector_type(8))) short short8;   // 8 bf16 (MFMA A/B frag)
typedef __attribute__((ext_vector_type(4))) short short4v;  // 4 bf16 (8B store)
typedef __attribute__((ext_vector_type(4))) float f32x4;    // MFMA C/D frag (16x16)
typedef __attribute__((ext_vector_type(16))) float f32x16;  // MFMA C/D frag (32x32)

// fp32 -> bf16 RNE (weight/output paths)
__device__ __forceinline__ short f2bf(float f) {
    union { float f; unsigned u; } x; x.f = f;
    unsigned u = x.u;
    return (short)((u + 0x7FFFu + ((u >> 16) & 1u)) >> 16);
}
// round-half-up variants (2 VALU; bias negligible for continuous data)
__device__ __forceinline__ short f2bf_ru(float f) {
    return (short)((__float_as_uint(f) + 0x8000u) >> 16);
}
__device__ __forceinline__ unsigned pk2bf(float a, float b) {
    unsigned ua = __float_as_uint(a) + 0x8000u;
    unsigned ub = __float_as_uint(b) + 0x8000u;
    return (ua >> 16) | (ub & 0xFFFF0000u);
}
// packed fp32x2 -> bf16x2 (a -> low short, b -> high short), single VALU op
__device__ __forceinline__ unsigned cvtpk(float a, float b) {
    unsigned r;
    asm("v_cvt_pk_bf16_f32 %0, %1, %2" : "=v"(r) : "v"(a), "v"(b));
    return r;
}
__device__ __forceinline__ float fexp2(float x) {
#if __has_builtin(__builtin_amdgcn_exp2f)
    return __builtin_amdgcn_exp2f(x);
#else
    return exp2f(x);
#endif
}
// async global->LDS, 16B per lane (wave-uniform base + lane*16 dest)
__device__ __forceinline__ void gload_lds16(const void* g, void* l) {
    __builtin_amdgcn_global_load_lds(
        (const __attribute__((address_space(1))) unsigned int*)g,
        (__attribute__((address_space(3))) unsigned int*)l, 16, 0, 0);
}

// ---------------------------------------------------------------------------
// Kernel 1: W [K][N] fp32 -> WT [N][K] bf16 for Wq/Wk/Wv (blockIdx.z)
// ---------------------------------------------------------------------------
__global__ void wt_kernel(const float* __restrict__ Wq, const float* __restrict__ Wk,
                          const float* __restrict__ Wv, short* __restrict__ wt_base) {
    __shared__ float t[32][33];
    const float* W = (blockIdx.z == 0) ? Wq : (blockIdx.z == 1 ? Wk : Wv);
    short* WT = wt_base + (size_t)blockIdx.z * DM * DM;
    int kb = blockIdx.x * 32, nb = blockIdx.y * 32;
    int tx = threadIdx.x, ty = threadIdx.y;  // 32 x 8
#pragma unroll
    for (int r = 0; r < 4; r++)
        t[ty + 8 * r][tx] = W[(size_t)(kb + ty + 8 * r) * DM + nb + tx];
    __syncthreads();
#pragma unroll
    for (int r = 0; r < 4; r++)
        WT[(size_t)(nb + ty + 8 * r) * DM + kb + tx] = f2bf(t[tx][ty + 8 * r]);
}

// ---------------------------------------------------------------------------
// Kernel 2: fused projections (z = 0:Q, 1:K, 2:V).  [frozen from R5]
// 512-thr blocks, tile 128(M) x 256(N), BK=32; 8 waves, each the m97 body.
// LDS 48KB x2buf -> 3 blocks/CU; grid 768 = one dispatch round, no tail.
// Staging issued at iter top. Grid 1D chunked XCD swizzle (768 = 8 x 96).
// ---------------------------------------------------------------------------
__global__ __launch_bounds__(512, 2) void projf_kernel(
        const float* __restrict__ Xq, const float* __restrict__ Xk,
        const float* __restrict__ Xv, const short* __restrict__ WT3,
        const float* __restrict__ bq, const float* __restrict__ bk,
        const float* __restrict__ bv,
        short* __restrict__ Qh, short* __restrict__ Kh, short* __restrict__ Vt,
        float qscale) {
    __shared__ __align__(16) short As[2][128 * 32];   // bf16 A tile,  8KB/buf
    __shared__ __align__(16) short Bs[2][256 * 32];   // bf16 B tile, 16KB/buf
    const int bid = blockIdx.x;
    const int swz = (bid & 7) * 96 + (bid >> 3);
    const int nx = swz & 3;          // n-tile (fastest logical: 4 share X panel)
    const int my = (swz >> 2) & 63;  // m-tile
    const int z  = swz >> 8;         // matrix select (4*64 = 256 per z)

    const float* X = (z == 0) ? Xq : (z == 1) ? Xk : Xv;
    const short* WT = WT3 + (size_t)z * DM * DM;
    const float* bias = (z == 0) ? bq : (z == 1) ? bk : bv;
    short* out = (z == 0) ? Qh : (z == 1) ? Kh : Vt;
    const float scale = (z == 0) ? qscale : 1.0f;
    const int mode = (z == 2);

    const int tid = threadIdx.x;
    const int lane = tid & 63, w = tid >> 6;          // 8 waves
    const int l15 = lane & 15, quad = lane >> 4;
    const int n0 = nx * 256, m0 = my * 128;
    const int wm = (w & 1) * 64, wn = (w >> 1) * 64;  // 2M x 4N wave grid
    const int arow = tid >> 2;          // A staging: 4 threads/row
    const int ako  = (tid & 3) * 8;     // 8 floats (=8 bf16 out) per thread

    const float* xb = X + (size_t)m0 * DM;

    f32x4 acc[4][4];
#pragma unroll
    for (int i = 0; i < 4; i++)
#pragma unroll
        for (int j = 0; j < 4; j++) { acc[i][j][0] = 0.f; acc[i][j][1] = 0.f; acc[i][j][2] = 0.f; acc[i][j][3] = 0.f; }

    auto stageB = [&](int k0, int bi) {
#pragma unroll
        for (int it = 0; it < 2; it++) {
            int c = it * 512 + tid;
            int row = c >> 2, ko = (c & 3) * 8;
            gload_lds16(WT + (size_t)(n0 + row) * DM + k0 + ko, Bs[bi] + c * 8);
        }
    };

    // ---- prologue: stage tile 0 into buf 0 ----
    float4 a0, a1;
    a0 = *(const float4*)(xb + (size_t)arow * DM + ako);
    a1 = *(const float4*)(xb + (size_t)arow * DM + ako + 4);
    stageB(0, 0);
    {
        uint4 p;
        p.x = pk2bf(a0.x, a0.y); p.y = pk2bf(a0.z, a0.w);
        p.z = pk2bf(a1.x, a1.y); p.w = pk2bf(a1.z, a1.w);
        *(uint4*)(As[0] + arow * 32 + ako) = p;
    }

    for (int t = 0; t < 32; t++) {
        const int bi = t & 1;
        const int kn = t * 32 + 32;     // next tile's k0
        __syncthreads();                // tile t staged (vmcnt+lgkm drained)

        if (t < 31) {                   // STAGE AT TOP: max cover before use
            a0 = *(const float4*)(xb + (size_t)arow * DM + kn + ako);
            a1 = *(const float4*)(xb + (size_t)arow * DM + kn + ako + 4);
            stageB(kn, bi ^ 1);
        }

        short8 af[4], bf[4];
#pragma unroll
        for (int i = 0; i < 4; i++)
            af[i] = *(const short8*)(As[bi] + (wm + i * 16 + l15) * 32 + quad * 8);
#pragma unroll
        for (int j = 0; j < 4; j++)
            bf[j] = *(const short8*)(Bs[bi] + (wn + j * 16 + l15) * 32 + quad * 8);

#pragma unroll
        for (int i = 0; i < 4; i++)
#pragma unroll
            for (int j = 0; j < 4; j++)
                acc[i][j] = __builtin_amdgcn_mfma_f32_16x16x32_bf16(af[i], bf[j], acc[i][j], 0, 0, 0);

        if (t < 31) {                   // convert+write A for tile t+1
            uint4 p;
            p.x = pk2bf(a0.x, a0.y); p.y = pk2bf(a0.z, a0.w);
            p.z = pk2bf(a1.x, a1.y); p.w = pk2bf(a1.z, a1.w);
            *(uint4*)(As[bi ^ 1] + arow * 32 + ako) = p;
        }
    }

    // ---- epilogue ----
#pragma unroll
    for (int j = 0; j < 4; j++) {
        int col = n0 + wn + j * 16 + l15;
        float bv_ = bias[col];
        int h = col >> 6, d = col & 63;
#pragma unroll
        for (int i = 0; i < 4; i++) {
            int rowbase = m0 + wm + i * 16 + quad * 4;
            int bb = rowbase >> 11, s0 = rowbase & 2047;
            if (mode == 0) {
#pragma unroll
                for (int r = 0; r < 4; r++)
                    out[((size_t)(bb * NH + h) * S_LEN + (s0 + r)) * HD + d] =
                        f2bf((acc[i][j][r] + bv_) * scale);
            } else {
                short4v pk;
#pragma unroll
                for (int r = 0; r < 4; r++) pk[r] = f2bf((acc[i][j][r] + bv_) * scale);
                *(short4v*)(out + ((size_t)(bb * NH + h) * HD + d) * S_LEN + s0) = pk;
            }
        }
    }
}

// ---------------------------------------------------------------------------
// Kernel 3: attention, R9: 32x32 MFMA + FULLY IN-REGISTER SOFTMAX (T12/m214).
// Swapped QK^T: s = mfma_32x32x16(K, Q) -> lane holds
//   P[key = (reg&3)+8*(reg>>2)+4*hi][q = lane&31]   (C/D map m74/m101)
// so the q-row sum is LANE-LOCAL (one shfl_xor(32) at the end), and the PV
// B-operand P[q=lane&31][key=16ks+hi*8+j] is built in-register per k-step:
//   c0..c3 = cvt_pk_bf16(pe pairs); swap(c0,c2); swap(c1,c3)   [VALU pipe]
// (v_permlane32_swap_b32: a.hi-lanes <-> b.lo-lanes; mapping cell-verified.)
// PV computes O^T = Vt . P^T (A=V-frag straight from the Vt layout); output
// is per-lane rows -> float4 stores scaled by the lane-local 1/l.
// DELETED vs R5: 36KB ps buffer, 32 scalar ds_write_b16/iter, per-iter
// lgkmcnt(0) drain, P ds_reads, end-of-loop shfl reductions.
// K/V LDS: [64][64] bf16 (8KB each, x2 buf = 32KB), source-preswizzled
// chunk^=(row&7) (rule 21); frag reads spread uniformly 8-deep over all 32
// banks = conflict-free minimum. 256 thr / 4 waves, q-tile 128; grid 1024 =
// 4 blocks/CU x 256 CU, one exact round, 4 independent barrier domains/CU.
// Grid 1D chunked XCD swizzle: 1024 = 8 XCDs x 128.
// ---------------------------------------------------------------------------
__global__ __launch_bounds__(256, 4) void attn_kernel(
        const short* __restrict__ Q, const short* __restrict__ K,
        const short* __restrict__ V, float* __restrict__ out) {
    __shared__ __align__(16) short Ks[2][64][64];  // [buf][key][d]   8KB/buf
    __shared__ __align__(16) short Vs[2][64][64];  // [buf][d][key]   8KB/buf
    const int bid = blockIdx.x;
    const int swz = (bid & 7) * 128 + (bid >> 3);
    const int qi = swz & 15;         // q-tile (fastest in logical order)
    const int h  = (swz >> 4) & 15;  // head
    const int b  = swz >> 8;         // batch

    const int tid = threadIdx.x;
    const int lane = tid & 63, w = tid >> 6;       // 4 waves
    const int l31 = lane & 31, hi = lane >> 5;
    const int q0 = qi * 128;
    const size_t bh = (size_t)(b * NH + h);
    const short* qp = Q + bh * S_LEN * HD;
    const short* kp = K + bh * S_LEN * HD;
    const short* vp = V + bh * (size_t)HD * S_LEN;

    // Q frags (B-operand, rows=q): qa[ks] = Q[q0+w*32+l31][ks*16 + hi*8 .. +8)
    short8 qa[4];
    {
        const short* qr = qp + (size_t)(q0 + w * 32 + l31) * HD + hi * 8;
#pragma unroll
        for (int ks = 0; ks < 4; ks++)
            qa[ks] = *(const short8*)(qr + ks * 16);
    }

    f32x16 o[2];
#pragma unroll
    for (int db = 0; db < 2; db++)
#pragma unroll
        for (int i = 0; i < 16; i++) o[db][i] = 0.f;
    float lsum = 0.f;

    // stage K tile [64 key][64 d] + V tile [64 d][64 key], 512 slots x 16B
    // each; LDS dest linear, global source chunk pre-swizzled (^ row&7).
    auto stageKV = [&](int kt, int bi) {
#pragma unroll
        for (int it = 0; it < 2; it++) {
            int c = it * 256 + tid;
            int row = c >> 3, ch = c & 7;
            int gc = ch ^ (row & 7);
            gload_lds16(kp + (size_t)(kt + row) * HD + gc * 8, &Ks[bi][0][0] + c * 8);
            gload_lds16(vp + (size_t)row * S_LEN + kt + gc * 8, &Vs[bi][0][0] + c * 8);
        }
    };

    stageKV(0, 0);

    for (int t = 0; t < 32; t++) {
        const int bi = t & 1;
        __syncthreads();                 // tile t ready (vmcnt drained); buf^1 free
        if (t < 31) stageKV((t + 1) << 6, bi ^ 1);   // issue next tile NOW

#pragma unroll
        for (int kb = 0; kb < 2; kb++) {
            // ---- K frags (A-operand, rows=key) + swapped QK^T ----
            const int krow = kb * 32 + l31;
            short8 kf[4];
#pragma unroll
            for (int ks = 0; ks < 4; ks++)
                kf[ks] = *(const short8*)(&Ks[bi][krow][((2 * ks + hi) ^ (krow & 7)) * 8]);
            f32x16 s;
#pragma unroll
            for (int i = 0; i < 16; i++) s[i] = 0.f;
            __builtin_amdgcn_s_setprio(1);
#pragma unroll
            for (int ks = 0; ks < 4; ks++)
                s = __builtin_amdgcn_mfma_f32_32x32x16_bf16(kf[ks], qa[ks], s, 0, 0, 0);
            __builtin_amdgcn_s_setprio(0);

            // ---- P = exp2(S'); lane-local q-row partial sum ----
            float pe[16];
#pragma unroll
            for (int i = 0; i < 16; i++) { pe[i] = fexp2(s[i]); lsum += pe[i]; }

            // ---- per k-step: build PV B-frag in-register, then PV ----
#pragma unroll
            for (int ksl = 0; ksl < 2; ksl++) {
                const int ks = 2 * kb + ksl;
                const int r0 = 8 * ksl;
                unsigned c0 = cvtpk(pe[r0 + 0], pe[r0 + 1]);
                unsigned c1 = cvtpk(pe[r0 + 2], pe[r0 + 3]);
                unsigned c2 = cvtpk(pe[r0 + 4], pe[r0 + 5]);
                unsigned c3 = cvtpk(pe[r0 + 6], pe[r0 + 7]);
                asm volatile("v_permlane32_swap_b32 %0, %1" : "+v"(c0), "+v"(c2));
                asm volatile("v_permlane32_swap_b32 %0, %1" : "+v"(c1), "+v"(c3));
                uint4 uu; uu.x = c0; uu.y = c1; uu.z = c2; uu.w = c3;
                short8 pb = *(short8*)&uu;
                __builtin_amdgcn_s_setprio(1);
#pragma unroll
                for (int db = 0; db < 2; db++) {
                    const int vrow = db * 32 + l31;
                    short8 vf = *(const short8*)(&Vs[bi][vrow][((2 * ks + hi) ^ (vrow & 7)) * 8]);
                    o[db] = __builtin_amdgcn_mfma_f32_32x32x16_bf16(vf, pb, o[db], 0, 0, 0);
                }
                __builtin_amdgcn_s_setprio(0);
            }
        }
    }

    // ---- lane-local l (combine the two key-halves) + epilogue ----
    float l = lsum + __shfl_xor(lsum, 32);
    float inv = 1.f / l;
    float* orow = out + ((size_t)b * S_LEN + q0 + w * 32 + l31) * DM + h * HD + hi * 4;
#pragma unroll
    for (int db = 0; db < 2; db++)
#pragma unroll
        for (int g = 0; g < 4; g++) {
            float4 v;
            v.x = o[db][4 * g + 0] * inv;
            v.y = o[db][4 * g + 1] * inv;
            v.z = o[db][4 * g + 2] * inv;
            v.w = o[db][4 * g + 3] * inv;
            *(float4*)(orow + db * 32 + g * 8) = v;   // d = 32db + 8g + 4hi + 0..3
        }
}

// ---------------------------------------------------------------------------
// ws (56.6 MB): [0,6.3M) WT x3 bf16 | Qh | Kh | Vt (16.8M each)
// ---------------------------------------------------------------------------
extern "C" void kernel_launch(void* const* d_in, const int* in_sizes, int n_in,
                              void* d_out, int out_size, void* d_ws, size_t ws_size,
                              hipStream_t stream) {
    const float* query  = (const float*)d_in[0];
    const float* key_in = (const float*)d_in[1];
    const float* value  = (const float*)d_in[2];
    const float* Wq = (const float*)d_in[3];
    const float* bq = (const float*)d_in[4];
    const float* Wk = (const float*)d_in[5];
    const float* bk = (const float*)d_in[6];
    const float* Wv = (const float*)d_in[7];
    const float* bv = (const float*)d_in[8];

    short* wt = (short*)d_ws;
    short* Qh = wt + 3 * 1048576;
    short* Kh = Qh + 8388608;
    short* Vt = Kh + 8388608;
    float* out = (float*)d_out;

    const float QSCALE = 0.125f * 1.44269504088896340736f;  // 1/sqrt(64) * log2(e)

    wt_kernel<<<dim3(32, 32, 3), dim3(32, 8), 0, stream>>>(Wq, Wk, Wv, wt);
    projf_kernel<<<dim3(768), 512, 0, stream>>>(query, key_in, value, wt,
                                                bq, bk, bv, Qh, Kh, Vt, QSCALE);
    attn_kernel<<<dim3(1024), 256, 0, stream>>>(Qh, Kh, Vt, out);
}